// Round 3
// baseline (151.478 us; speedup 1.0000x reference)
//
#include <hip/hip_runtime.h>
#include <stdint.h>

#define N_ROWS 4096
#define DIM    1024
#define NCLS   64
#define EPSV   0.1f

typedef __attribute__((ext_vector_type(8))) __bf16 bf16x8;
typedef __attribute__((ext_vector_type(4))) float  f32x4;

__device__ __forceinline__ unsigned short f2bf(float f) {
    union { float f; unsigned u; } v; v.f = f;
    unsigned r = v.u + 0x7FFF + ((v.u >> 16) & 1);   // RNE
    return (unsigned short)(r >> 16);
}

__device__ __forceinline__ void async_cp16(const void* g, void* l) {
    __builtin_amdgcn_global_load_lds((const __attribute__((address_space(1))) void*)g,
                                     (__attribute__((address_space(3))) void*)l,
                                     16, 0, 0);
}

__device__ __forceinline__ float softplus(float x) {
    return fmaxf(x, 0.f) + __logf(1.f + __expf(-fabsf(x)));
}

// ---------------- K1: per-chunk per-class sum + sqsum partials ---------------
// grid: 8 dim-groups (128 dims) x 32 row-chunks (128 rows) = 256 blocks, 128 thr
__global__ __launch_bounds__(128) void k_stats(const float* __restrict__ X,
                                               const int* __restrict__ tgt,
                                               float* __restrict__ csum_p,
                                               float* __restrict__ csq_p) {
    __shared__ float csum[NCLS * 128];
    __shared__ float csq[NCLS * 128];
    __shared__ int   tch[128];
    int tid = threadIdx.x;
    int dg = blockIdx.x >> 5, ch = blockIdx.x & 31;
    int d = dg * 128 + tid;
    for (int c = 0; c < NCLS; c++) { csum[c * 128 + tid] = 0.f; csq[c * 128 + tid] = 0.f; }
    tch[tid] = tgt[ch * 128 + tid];
    __syncthreads();
    const float* xp = X + (size_t)(ch * 128) * DIM + d;
    #pragma unroll 4
    for (int r = 0; r < 128; r++) {
        float x = xp[(size_t)r * DIM];
        int t = tch[r];
        csum[t * 128 + tid] += x;          // thread owns its column: no race
        csq [t * 128 + tid] += x * x;
    }
    for (int c = 0; c < NCLS; c++) {
        csum_p[(size_t)(ch * NCLS + c) * DIM + d] = csum[c * 128 + tid];
        csq_p [(size_t)(ch * NCLS + c) * DIM + d] = csq [c * 128 + tid];
    }
}

// ---------------- K2: reduce partials over 32 chunks -------------------------
__global__ __launch_bounds__(256) void k_reduce(const float* __restrict__ csum_p,
                                                const float* __restrict__ csq_p,
                                                float* __restrict__ csumR,
                                                float* __restrict__ csqR) {
    int idx = blockIdx.x * 256 + threadIdx.x;   // (c,d) flat, 65536
    float s = 0.f, q = 0.f;
    #pragma unroll 8
    for (int ch = 0; ch < 32; ch++) {
        s += csum_p[(size_t)ch * NCLS * DIM + idx];
        q += csq_p [(size_t)ch * NCLS * DIM + idx];
    }
    csumR[idx] = s;
    csqR [idx] = q;
}

// ---------------- K3: counts (redundant per block) + weights + zero loss -----
__global__ __launch_bounds__(256) void k_weights(const int* __restrict__ tgt,
                                                 const float* __restrict__ csumR,
                                                 const float* __restrict__ csqR,
                                                 float* __restrict__ w,
                                                 float* __restrict__ loss_out) {
    __shared__ int hist[NCLS];
    int tid = threadIdx.x;
    if (tid < NCLS) hist[tid] = 0;
    __syncthreads();
    for (int i = tid; i < N_ROWS; i += 256) atomicAdd(&hist[tgt[i]], 1);
    __syncthreads();
    float cnt_pos, cnt_neg;
    {
        long long sp = 0, ss = 0;
        for (int c = 0; c < NCLS; c++) { long long cc = hist[c]; sp += cc * (cc - 1); ss += cc * cc; }
        cnt_pos = (float)sp;
        cnt_neg = (float)((long long)N_ROWS * N_ROWS - ss);
    }
    int d = blockIdx.x * 256 + tid;             // 0..1023
    float A = 0.f, X2 = 0.f, T = 0.f, SS = 0.f;
    #pragma unroll 8
    for (int c = 0; c < NCLS; c++) {
        float s = csumR[c * DIM + d];
        float q = csqR [c * DIM + d];
        A += (float)hist[c] * q; X2 += q; T += s; SS += s * s;
    }
    float posnum = 2.f * (A - SS);
    float negnum = 2.f * ((float)N_ROWS * X2 - A - T * T + SS);
    w[d] = cnt_neg / (negnum + EPSV) - cnt_pos / (posnum + EPSV);
    if (blockIdx.x == 0 && tid == 0) loss_out[0] = 0.0f;
}

// ---------------- K4: xw, sq, bf16 casts -------------------------------------
__global__ __launch_bounds__(256) void k_prep(const float* __restrict__ X,
                                              const float* __restrict__ w,
                                              unsigned short* __restrict__ Xb,
                                              unsigned short* __restrict__ XWb,
                                              float* __restrict__ sq) {
    int row = blockIdx.x, tid = threadIdx.x;
    const float4* xr = (const float4*)(X + (size_t)row * DIM);
    const float4* wr = (const float4*)w;
    float4 x = xr[tid], ww = wr[tid];
    float4 xw = make_float4(x.x * ww.x, x.y * ww.y, x.z * ww.z, x.w * ww.w);
    float p = x.x * xw.x + x.y * xw.y + x.z * xw.z + x.w * xw.w;
    ushort4 xb, xwb;
    xb.x  = f2bf(x.x);  xb.y  = f2bf(x.y);  xb.z  = f2bf(x.z);  xb.w  = f2bf(x.w);
    xwb.x = f2bf(xw.x); xwb.y = f2bf(xw.y); xwb.z = f2bf(xw.z); xwb.w = f2bf(xw.w);
    ((ushort4*)(Xb  + (size_t)row * DIM))[tid] = xb;
    ((ushort4*)(XWb + (size_t)row * DIM))[tid] = xwb;
    for (int off = 32; off; off >>= 1) p += __shfl_down(p, off, 64);
    __shared__ float red[4];
    int wv = tid >> 6, ln = tid & 63;
    if (ln == 0) red[wv] = p;
    __syncthreads();
    if (tid == 0) sq[row] = red[0] + red[1] + red[2] + red[3];
}

// ---------------- K5: fused bf16 MFMA gram + softplus + masked mean ----------
// 528 upper-triangular 128x128 tiles; 256 thr = 4 waves, each wave 64x64
// (4x4 MFMA frags, 16 MFMA + 8 ds_read_b128 per K-step). Depth-1
// double-buffered global_load_lds staging, single barrier per K-step.
__global__ __launch_bounds__(256) void k_gemm_loss(const unsigned short* __restrict__ Xb,
                                                   const unsigned short* __restrict__ XWb,
                                                   const float* __restrict__ sq,
                                                   const int* __restrict__ tgt,
                                                   float* __restrict__ loss) {
    __shared__ __align__(16) unsigned short As[2][128 * 32];
    __shared__ __align__(16) unsigned short Bs[2][128 * 32];
    __shared__ float sqI[128], sqJ[128];
    __shared__ int   tIs[128], tJs[128];
    __shared__ float red[4];

    int tid = threadIdx.x;
    int wave = tid >> 6, lane = tid & 63;

    // decode triangular (it, jt), jt >= it
    int b = blockIdx.x, it = 0, rl = 32;
    while (b >= rl) { b -= rl; rl--; it++; }
    int jt = it + b;

    // staging: 16 global_load_lds(16B) per K-step, 4 per wave.
    // XOR-quad swizzle: logical quad q stored at physical quad p = q ^ ((row>>1)&3)
    const unsigned short* gp[4];
    unsigned short* lb[4];
    #pragma unroll
    for (int s = 0; s < 4; s++) {
        int gI = wave * 4 + s;              // 0..15 : <8 -> A tile, >=8 -> B tile
        int R  = gI * 16 + (lane >> 2);     // staging row 0..255
        int q  = (lane & 3) ^ ((R >> 1) & 3);
        int r  = R & 127;
        bool isA = R < 128;
        int grow = (isA ? it : jt) * 128 + r;
        const unsigned short* src = isA ? Xb : XWb;
        gp[s] = src + (size_t)grow * DIM + q * 8;
        lb[s] = (isA ? &As[0][0] : &Bs[0][0]) + (gI & 7) * (16 * 32);
    }

    // fragment LDS offsets (constant over k): A[m=lane&15][k=(lane>>4)*8+j]
    int lr = lane & 15, kq = lane >> 4;
    int offA[4], offB[4];
    int wrow = (wave >> 1) * 64, wcol = (wave & 1) * 64;
    #pragma unroll
    for (int mi = 0; mi < 4; mi++) {
        int row = wrow + mi * 16 + lr;
        offA[mi] = row * 32 + (kq ^ ((row >> 1) & 3)) * 8;
        int col = wcol + mi * 16 + lr;
        offB[mi] = col * 32 + (kq ^ ((col >> 1) & 3)) * 8;
    }

    f32x4 acc[4][4];
    #pragma unroll
    for (int i = 0; i < 4; i++)
        #pragma unroll
        for (int j = 0; j < 4; j++) acc[i][j] = (f32x4){0.f, 0.f, 0.f, 0.f};

    // prologue: stage K-step 0 into buffer 0
    #pragma unroll
    for (int s = 0; s < 4; s++) async_cp16(gp[s], lb[s]);

    for (int kk = 0; kk < 32; kk++) {
        int buf = kk & 1;
        __syncthreads();                    // drains vmcnt: step-kk staging done
        if (kk < 31) {                      // prefetch kk+1 into other buffer,
            #pragma unroll                  // overlaps this step's 16 MFMAs
            for (int s = 0; s < 4; s++)
                async_cp16(gp[s] + (kk + 1) * 32, lb[s] + (buf ^ 1) * (128 * 32));
        }
        const unsigned short* Ab = As[buf];
        const unsigned short* Bb = Bs[buf];
        bf16x8 av[4], bv[4];
        #pragma unroll
        for (int i = 0; i < 4; i++) {
            av[i] = *(const bf16x8*)(Ab + offA[i]);
            bv[i] = *(const bf16x8*)(Bb + offB[i]);
        }
        #pragma unroll
        for (int i = 0; i < 4; i++)
            #pragma unroll
            for (int j = 0; j < 4; j++)
                acc[i][j] = __builtin_amdgcn_mfma_f32_16x16x32_bf16(av[i], bv[j], acc[i][j], 0, 0, 0);
    }

    // epilogue: S = sq_i + sq_j - 2G, masked softplus, symmetric x2 off-diagonal
    if (tid < 128) { sqI[tid] = sq[it * 128 + tid]; tIs[tid] = tgt[it * 128 + tid]; }
    else { int u = tid - 128; sqJ[u] = sq[jt * 128 + u]; tJs[u] = tgt[jt * 128 + u]; }
    __syncthreads();

    float sum = 0.f;
    bool diagTile = (it == jt);
    #pragma unroll
    for (int j = 0; j < 4; j++) {
        int col = wcol + j * 16 + (lane & 15);            // C/D: col = lane&15
        float sj = sqJ[col]; int tj = tJs[col];
        #pragma unroll
        for (int i = 0; i < 4; i++) {
            int rbase = wrow + i * 16 + (lane >> 4) * 4;  // C/D: row = quad*4+reg
            #pragma unroll
            for (int r = 0; r < 4; r++) {
                int rowp = rbase + r;
                float S = sqI[rowp] + sj - 2.f * acc[i][j][r];
                float v;
                if (tIs[rowp] == tj) v = (diagTile && rowp == col) ? 0.f : softplus(-S);
                else                 v = softplus(S);
                sum += v;
            }
        }
    }
    float scale = (diagTile ? 1.f : 2.f) * (1.f / ((float)N_ROWS * (float)(N_ROWS - 1)));
    sum *= scale;
    for (int off = 32; off; off >>= 1) sum += __shfl_down(sum, off, 64);
    if (lane == 0) red[wave] = sum;
    __syncthreads();
    if (tid == 0) atomicAdd(loss, red[0] + red[1] + red[2] + red[3]);
}

extern "C" void kernel_launch(void* const* d_in, const int* in_sizes, int n_in,
                              void* d_out, int out_size, void* d_ws, size_t ws_size,
                              hipStream_t stream) {
    const float* X  = (const float*)d_in[0];
    const int* tgt  = (const int*)d_in[1];
    float* out = (float*)d_out;
    char* ws = (char*)d_ws;
    const size_t MB = 1u << 20;

    float* w        = (float*)ws;                       // 4 KB
    float* sq       = (float*)(ws + 4096);              // 16 KB
    unsigned short* Xb  = (unsigned short*)(ws + 1 * MB);   // 8 MB
    unsigned short* XWb = (unsigned short*)(ws + 9 * MB);   // 8 MB
    float* csum_p   = (float*)(ws + 17 * MB);           // 8 MB
    float* csq_p    = (float*)(ws + 25 * MB);           // 8 MB
    float* csumR    = (float*)(ws + 33 * MB);           // 256 KB
    float* csqR     = (float*)(ws + 33 * MB + 256 * 1024); // 256 KB

    k_stats   <<<256,  128, 0, stream>>>(X, tgt, csum_p, csq_p);
    k_reduce  <<<256,  256, 0, stream>>>(csum_p, csq_p, csumR, csqR);
    k_weights <<<4,    256, 0, stream>>>(tgt, csumR, csqR, w, out);
    k_prep    <<<4096, 256, 0, stream>>>(X, w, Xb, XWb, sq);
    k_gemm_loss<<<528, 256, 0, stream>>>(Xb, XWb, sq, tgt, out);
}

// Round 4
// 136.186 us; speedup vs baseline: 1.1123x; 1.1123x over previous
//
#include <hip/hip_runtime.h>
#include <stdint.h>

#define N_ROWS 4096
#define DIM    1024
#define NCLS   64
#define EPSV   0.1f

typedef __attribute__((ext_vector_type(8))) __bf16 bf16x8;
typedef __attribute__((ext_vector_type(4))) float  f32x4;

__device__ __forceinline__ unsigned short f2bf(float f) {
    union { float f; unsigned u; } v; v.f = f;
    unsigned r = v.u + 0x7FFF + ((v.u >> 16) & 1);   // RNE
    return (unsigned short)(r >> 16);
}

__device__ __forceinline__ void async_cp16(const void* g, void* l) {
    __builtin_amdgcn_global_load_lds((const __attribute__((address_space(1))) void*)g,
                                     (__attribute__((address_space(3))) void*)l,
                                     16, 0, 0);
}

__device__ __forceinline__ float softplus(float x) {
    return fmaxf(x, 0.f) + __logf(1.f + __expf(-fabsf(x)));
}

// ---------------- K1: per-chunk per-class sum + sqsum partials ---------------
__global__ __launch_bounds__(128) void k_stats(const float* __restrict__ X,
                                               const int* __restrict__ tgt,
                                               float* __restrict__ csum_p,
                                               float* __restrict__ csq_p) {
    __shared__ float csum[NCLS * 128];
    __shared__ float csq[NCLS * 128];
    __shared__ int   tch[128];
    int tid = threadIdx.x;
    int dg = blockIdx.x >> 5, ch = blockIdx.x & 31;
    int d = dg * 128 + tid;
    for (int c = 0; c < NCLS; c++) { csum[c * 128 + tid] = 0.f; csq[c * 128 + tid] = 0.f; }
    tch[tid] = tgt[ch * 128 + tid];
    __syncthreads();
    const float* xp = X + (size_t)(ch * 128) * DIM + d;
    #pragma unroll 4
    for (int r = 0; r < 128; r++) {
        float x = xp[(size_t)r * DIM];
        int t = tch[r];
        csum[t * 128 + tid] += x;          // thread owns its column: no race
        csq [t * 128 + tid] += x * x;
    }
    for (int c = 0; c < NCLS; c++) {
        csum_p[(size_t)(ch * NCLS + c) * DIM + d] = csum[c * 128 + tid];
        csq_p [(size_t)(ch * NCLS + c) * DIM + d] = csq [c * 128 + tid];
    }
}

// ---------------- K2: reduce partials over 32 chunks -------------------------
__global__ __launch_bounds__(256) void k_reduce(const float* __restrict__ csum_p,
                                                const float* __restrict__ csq_p,
                                                float* __restrict__ csumR,
                                                float* __restrict__ csqR) {
    int idx = blockIdx.x * 256 + threadIdx.x;   // (c,d) flat, 65536
    float s = 0.f, q = 0.f;
    #pragma unroll 8
    for (int ch = 0; ch < 32; ch++) {
        s += csum_p[(size_t)ch * NCLS * DIM + idx];
        q += csq_p [(size_t)ch * NCLS * DIM + idx];
    }
    csumR[idx] = s;
    csqR [idx] = q;
}

// ---------------- K3: counts (redundant per block) + weights + zero loss -----
__global__ __launch_bounds__(256) void k_weights(const int* __restrict__ tgt,
                                                 const float* __restrict__ csumR,
                                                 const float* __restrict__ csqR,
                                                 float* __restrict__ w,
                                                 float* __restrict__ loss_out) {
    __shared__ int hist[NCLS];
    int tid = threadIdx.x;
    if (tid < NCLS) hist[tid] = 0;
    __syncthreads();
    for (int i = tid; i < N_ROWS; i += 256) atomicAdd(&hist[tgt[i]], 1);
    __syncthreads();
    float cnt_pos, cnt_neg;
    {
        long long sp = 0, ss = 0;
        for (int c = 0; c < NCLS; c++) { long long cc = hist[c]; sp += cc * (cc - 1); ss += cc * cc; }
        cnt_pos = (float)sp;
        cnt_neg = (float)((long long)N_ROWS * N_ROWS - ss);
    }
    int d = blockIdx.x * 256 + tid;             // 0..1023
    float A = 0.f, X2 = 0.f, T = 0.f, SS = 0.f;
    #pragma unroll 8
    for (int c = 0; c < NCLS; c++) {
        float s = csumR[c * DIM + d];
        float q = csqR [c * DIM + d];
        A += (float)hist[c] * q; X2 += q; T += s; SS += s * s;
    }
    float posnum = 2.f * (A - SS);
    float negnum = 2.f * ((float)N_ROWS * X2 - A - T * T + SS);
    w[d] = cnt_neg / (negnum + EPSV) - cnt_pos / (posnum + EPSV);
    if (blockIdx.x == 0 && tid == 0) loss_out[0] = 0.0f;
}

// ---------------- K4: xw, sq, bf16 casts -------------------------------------
__global__ __launch_bounds__(256) void k_prep(const float* __restrict__ X,
                                              const float* __restrict__ w,
                                              unsigned short* __restrict__ Xb,
                                              unsigned short* __restrict__ XWb,
                                              float* __restrict__ sq) {
    int row = blockIdx.x, tid = threadIdx.x;
    const float4* xr = (const float4*)(X + (size_t)row * DIM);
    const float4* wr = (const float4*)w;
    float4 x = xr[tid], ww = wr[tid];
    float4 xw = make_float4(x.x * ww.x, x.y * ww.y, x.z * ww.z, x.w * ww.w);
    float p = x.x * xw.x + x.y * xw.y + x.z * xw.z + x.w * xw.w;
    ushort4 xb, xwb;
    xb.x  = f2bf(x.x);  xb.y  = f2bf(x.y);  xb.z  = f2bf(x.z);  xb.w  = f2bf(x.w);
    xwb.x = f2bf(xw.x); xwb.y = f2bf(xw.y); xwb.z = f2bf(xw.z); xwb.w = f2bf(xw.w);
    ((ushort4*)(Xb  + (size_t)row * DIM))[tid] = xb;
    ((ushort4*)(XWb + (size_t)row * DIM))[tid] = xwb;
    for (int off = 32; off; off >>= 1) p += __shfl_down(p, off, 64);
    __shared__ float red[4];
    int wv = tid >> 6, ln = tid & 63;
    if (ln == 0) red[wv] = p;
    __syncthreads();
    if (tid == 0) sq[row] = red[0] + red[1] + red[2] + red[3];
}

// ---------------- K5: fused bf16 MFMA gram + softplus + masked mean ----------
// 128x128 tiles, upper-triangular, jt-major XCD grouping: 640 slots = 8 groups
// x 80; group g = blockIdx&7 owns columns jt in {g, g+8, g+16, g+24} (B-slab
// L2 locality per XCD). 512 thr = 8 waves, wave = 64x32 (4x2 frags).
// Depth-2 pipeline: 3 LDS buffers, raw s_barrier + manual vmcnt(2).
__global__ __launch_bounds__(512) void k_gemm_loss(const unsigned short* __restrict__ Xb,
                                                   const unsigned short* __restrict__ XWb,
                                                   const float* __restrict__ sq,
                                                   const int* __restrict__ tgt,
                                                   float* __restrict__ loss) {
    __shared__ __align__(16) unsigned short As[3][128 * 32];
    __shared__ __align__(16) unsigned short Bs[3][128 * 32];
    __shared__ float sqI[128], sqJ[128];
    __shared__ int   tIs[128], tJs[128];
    __shared__ float red[8];

    int tid = threadIdx.x;
    int wave = tid >> 6, lane = tid & 63;

    // decode (group g, slot s) -> (it, jt), jt >= it
    int g = blockIdx.x & 7, s = blockIdx.x >> 3;
    int sz0 = g + 1, sz1 = g + 9, sz2 = g + 17, sz3 = g + 25;
    int jt, it;
    if      (s < sz0)             { jt = g;      it = s; }
    else if (s < sz0 + sz1)       { jt = g + 8;  it = s - sz0; }
    else if (s < sz0 + sz1 + sz2) { jt = g + 16; it = s - sz0 - sz1; }
    else if (s < sz0 + sz1 + sz2 + sz3) { jt = g + 24; it = s - sz0 - sz1 - sz2; }
    else return;                                    // 112 idle filler blocks

    // staging: 16 global_load_lds(16B) per K-step, 2 per wave.
    // XOR-quad swizzle: logical quad q stored at physical quad p = q ^ ((row>>1)&3)
    const unsigned short* gp[2];
    unsigned short* lb[2];
    #pragma unroll
    for (int si = 0; si < 2; si++) {
        int gI = wave * 2 + si;             // 0..15 : <8 -> A tile, >=8 -> B tile
        int R  = gI * 16 + (lane >> 2);     // staging row 0..255
        int q  = (lane & 3) ^ ((R >> 1) & 3);
        int r  = R & 127;
        bool isA = R < 128;
        int grow = (isA ? it : jt) * 128 + r;
        const unsigned short* src = isA ? Xb : XWb;
        gp[si] = src + (size_t)grow * DIM + q * 8;
        lb[si] = (isA ? &As[0][0] : &Bs[0][0]) + (gI & 7) * (16 * 32);
    }

    // fragment LDS offsets (constant over k): A[m=lane&15][k=(lane>>4)*8+j]
    int lr = lane & 15, kq = lane >> 4;
    int offA[4], offB[2];
    int wrow = (wave >> 2) * 64, wcol = (wave & 3) * 32;
    #pragma unroll
    for (int mi = 0; mi < 4; mi++) {
        int row = wrow + mi * 16 + lr;
        offA[mi] = row * 32 + (kq ^ ((row >> 1) & 3)) * 8;
    }
    #pragma unroll
    for (int nj = 0; nj < 2; nj++) {
        int col = wcol + nj * 16 + lr;
        offB[nj] = col * 32 + (kq ^ ((col >> 1) & 3)) * 8;
    }

    f32x4 acc[4][2];
    #pragma unroll
    for (int i = 0; i < 4; i++)
        #pragma unroll
        for (int j = 0; j < 2; j++) acc[i][j] = (f32x4){0.f, 0.f, 0.f, 0.f};

    // prologue: stage K-steps 0,1 into buffers 0,1  (4 loads in flight/wave)
    #pragma unroll
    for (int si = 0; si < 2; si++) async_cp16(gp[si], lb[si]);
    #pragma unroll
    for (int si = 0; si < 2; si++) async_cp16(gp[si] + 32, lb[si] + 128 * 32);

    int rd = 0;                             // read-buffer index = kk % 3
    for (int kk = 0; kk < 32; kk++) {
        // wait this step's staging (leave next step's 2 loads in flight)
        if (kk != 31) asm volatile("s_waitcnt vmcnt(2)" ::: "memory");
        else          asm volatile("s_waitcnt vmcnt(0)" ::: "memory");
        asm volatile("s_barrier" ::: "memory");
        if (kk < 30) {                      // prefetch kk+2 into (kk+2)%3
            int wr = rd ? rd - 1 : 2;       // (rd+2)%3
            #pragma unroll
            for (int si = 0; si < 2; si++)
                async_cp16(gp[si] + (kk + 2) * 32, lb[si] + wr * (128 * 32));
        }
        const unsigned short* Ab = As[rd];
        const unsigned short* Bb = Bs[rd];
        bf16x8 av[4], bv[2];
        #pragma unroll
        for (int i = 0; i < 4; i++) av[i] = *(const bf16x8*)(Ab + offA[i]);
        #pragma unroll
        for (int j = 0; j < 2; j++) bv[j] = *(const bf16x8*)(Bb + offB[j]);
        #pragma unroll
        for (int i = 0; i < 4; i++)
            #pragma unroll
            for (int j = 0; j < 2; j++)
                acc[i][j] = __builtin_amdgcn_mfma_f32_16x16x32_bf16(av[i], bv[j], acc[i][j], 0, 0, 0);
        rd = (rd == 2) ? 0 : rd + 1;
    }

    // epilogue: S = sq_i + sq_j - 2G, masked softplus, symmetric x2 off-diagonal
    __syncthreads();
    if (tid < 128)      { sqI[tid] = sq[it * 128 + tid]; tIs[tid] = tgt[it * 128 + tid]; }
    else if (tid < 256) { int u = tid - 128; sqJ[u] = sq[jt * 128 + u]; tJs[u] = tgt[jt * 128 + u]; }
    __syncthreads();

    float sum = 0.f;
    bool diagTile = (it == jt);
    #pragma unroll
    for (int j = 0; j < 2; j++) {
        int col = wcol + j * 16 + (lane & 15);            // C/D: col = lane&15
        float sj = sqJ[col]; int tj = tJs[col];
        #pragma unroll
        for (int i = 0; i < 4; i++) {
            int rbase = wrow + i * 16 + (lane >> 4) * 4;  // C/D: row = quad*4+reg
            #pragma unroll
            for (int r = 0; r < 4; r++) {
                int rowp = rbase + r;
                float S = sqI[rowp] + sj - 2.f * acc[i][j][r];
                float v;
                if (tIs[rowp] == tj) v = (diagTile && rowp == col) ? 0.f : softplus(-S);
                else                 v = softplus(S);
                sum += v;
            }
        }
    }
    float scale = (diagTile ? 1.f : 2.f) * (1.f / ((float)N_ROWS * (float)(N_ROWS - 1)));
    sum *= scale;
    for (int off = 32; off; off >>= 1) sum += __shfl_down(sum, off, 64);
    if (lane == 0) red[wave] = sum;
    __syncthreads();
    if (tid == 0) {
        float t = 0.f;
        #pragma unroll
        for (int wv = 0; wv < 8; wv++) t += red[wv];
        atomicAdd(loss, t);
    }
}

extern "C" void kernel_launch(void* const* d_in, const int* in_sizes, int n_in,
                              void* d_out, int out_size, void* d_ws, size_t ws_size,
                              hipStream_t stream) {
    const float* X  = (const float*)d_in[0];
    const int* tgt  = (const int*)d_in[1];
    float* out = (float*)d_out;
    char* ws = (char*)d_ws;
    const size_t MB = 1u << 20;

    float* w        = (float*)ws;                       // 4 KB
    float* sq       = (float*)(ws + 4096);              // 16 KB
    unsigned short* Xb  = (unsigned short*)(ws + 1 * MB);   // 8 MB
    unsigned short* XWb = (unsigned short*)(ws + 9 * MB);   // 8 MB
    float* csum_p   = (float*)(ws + 17 * MB);           // 8 MB
    float* csq_p    = (float*)(ws + 25 * MB);           // 8 MB
    float* csumR    = (float*)(ws + 33 * MB);           // 256 KB
    float* csqR     = (float*)(ws + 33 * MB + 256 * 1024); // 256 KB

    k_stats   <<<256,  128, 0, stream>>>(X, tgt, csum_p, csq_p);
    k_reduce  <<<256,  256, 0, stream>>>(csum_p, csq_p, csumR, csqR);
    k_weights <<<4,    256, 0, stream>>>(tgt, csumR, csqR, w, out);
    k_prep    <<<4096, 256, 0, stream>>>(X, w, Xb, XWb, sq);
    k_gemm_loss<<<640, 512, 0, stream>>>(Xb, XWb, sq, tgt, out);
}

// Round 5
// 127.919 us; speedup vs baseline: 1.1842x; 1.0646x over previous
//
#include <hip/hip_runtime.h>
#include <stdint.h>

#define N_ROWS 4096
#define DIM    1024
#define NCLS   64
#define EPSV   0.1f

typedef __attribute__((ext_vector_type(8))) __bf16 bf16x8;
typedef __attribute__((ext_vector_type(4))) float  f32x4;

__device__ __forceinline__ unsigned short f2bf(float f) {
    union { float f; unsigned u; } v; v.f = f;
    unsigned r = v.u + 0x7FFF + ((v.u >> 16) & 1);   // RNE
    return (unsigned short)(r >> 16);
}

__device__ __forceinline__ void async_cp16(const void* g, void* l) {
    __builtin_amdgcn_global_load_lds((const __attribute__((address_space(1))) void*)g,
                                     (__attribute__((address_space(3))) void*)l,
                                     16, 0, 0);
}

__device__ __forceinline__ float softplus(float x) {
    return fmaxf(x, 0.f) + __logf(1.f + __expf(-fabsf(x)));
}

// ---------------- K1: per-class sum/sqsum via row gather ---------------------
// grid 256 = (class c) x (dim quarter q); writes csumR/csqR directly.
__global__ __launch_bounds__(256) void k_cstats(const float* __restrict__ X,
                                                const int* __restrict__ tgt,
                                                float* __restrict__ csumR,
                                                float* __restrict__ csqR) {
    __shared__ int rows[N_ROWS];
    __shared__ int nrows_s;
    int tid = threadIdx.x;
    int c = blockIdx.x >> 2, q = blockIdx.x & 3;
    if (tid == 0) nrows_s = 0;
    __syncthreads();
    for (int i = tid; i < N_ROWS; i += 256)
        if (tgt[i] == c) { int p = atomicAdd(&nrows_s, 1); rows[p] = i; }
    __syncthreads();
    int n = nrows_s;
    int d = q * 256 + tid;
    float s = 0.f, qq = 0.f;
    #pragma unroll 4
    for (int r = 0; r < n; r++) {
        float x = X[(size_t)rows[r] * DIM + d];
        s += x; qq += x * x;
    }
    csumR[c * DIM + d] = s;
    csqR [c * DIM + d] = qq;
}

// ---------------- K2: counts (redundant per block) + weights + zero loss -----
__global__ __launch_bounds__(256) void k_weights(const int* __restrict__ tgt,
                                                 const float* __restrict__ csumR,
                                                 const float* __restrict__ csqR,
                                                 float* __restrict__ w,
                                                 float* __restrict__ loss_out) {
    __shared__ int hist[NCLS];
    int tid = threadIdx.x;
    if (tid < NCLS) hist[tid] = 0;
    __syncthreads();
    for (int i = tid; i < N_ROWS; i += 256) atomicAdd(&hist[tgt[i]], 1);
    __syncthreads();
    float cnt_pos, cnt_neg;
    {
        long long sp = 0, ss = 0;
        for (int c = 0; c < NCLS; c++) { long long cc = hist[c]; sp += cc * (cc - 1); ss += cc * cc; }
        cnt_pos = (float)sp;
        cnt_neg = (float)((long long)N_ROWS * N_ROWS - ss);
    }
    int d = blockIdx.x * 256 + tid;             // 0..1023
    float A = 0.f, X2 = 0.f, T = 0.f, SS = 0.f;
    #pragma unroll 8
    for (int c = 0; c < NCLS; c++) {
        float s = csumR[c * DIM + d];
        float q = csqR [c * DIM + d];
        A += (float)hist[c] * q; X2 += q; T += s; SS += s * s;
    }
    float posnum = 2.f * (A - SS);
    float negnum = 2.f * ((float)N_ROWS * X2 - A - T * T + SS);
    w[d] = cnt_neg / (negnum + EPSV) - cnt_pos / (posnum + EPSV);
    if (blockIdx.x == 0 && tid == 0) loss_out[0] = 0.0f;
}

// ---------------- K3: xw, sq, bf16 casts -------------------------------------
__global__ __launch_bounds__(256) void k_prep(const float* __restrict__ X,
                                              const float* __restrict__ w,
                                              unsigned short* __restrict__ Xb,
                                              unsigned short* __restrict__ XWb,
                                              float* __restrict__ sq) {
    int row = blockIdx.x, tid = threadIdx.x;
    const float4* xr = (const float4*)(X + (size_t)row * DIM);
    const float4* wr = (const float4*)w;
    float4 x = xr[tid], ww = wr[tid];
    float4 xw = make_float4(x.x * ww.x, x.y * ww.y, x.z * ww.z, x.w * ww.w);
    float p = x.x * xw.x + x.y * xw.y + x.z * xw.z + x.w * xw.w;
    ushort4 xb, xwb;
    xb.x  = f2bf(x.x);  xb.y  = f2bf(x.y);  xb.z  = f2bf(x.z);  xb.w  = f2bf(x.w);
    xwb.x = f2bf(xw.x); xwb.y = f2bf(xw.y); xwb.z = f2bf(xw.z); xwb.w = f2bf(xw.w);
    ((ushort4*)(Xb  + (size_t)row * DIM))[tid] = xb;
    ((ushort4*)(XWb + (size_t)row * DIM))[tid] = xwb;
    for (int off = 32; off; off >>= 1) p += __shfl_down(p, off, 64);
    __shared__ float red[4];
    int wv = tid >> 6, ln = tid & 63;
    if (ln == 0) red[wv] = p;
    __syncthreads();
    if (tid == 0) sq[row] = red[0] + red[1] + red[2] + red[3];
}

// ---------------- K4: fused bf16 MFMA gram + softplus + masked mean ----------
// 128x128 tiles, upper-triangular, jt-major XCD grouping (640 slots = 8 x 80).
// 512 thr = 8 waves, wave = 64x32 (4x2 frags). Depth-3 pipeline: 4 LDS
// buffer pairs, raw s_barrier + manual s_waitcnt vmcnt(4).
__global__ __launch_bounds__(512) void k_gemm_loss(const unsigned short* __restrict__ Xb,
                                                   const unsigned short* __restrict__ XWb,
                                                   const float* __restrict__ sq,
                                                   const int* __restrict__ tgt,
                                                   float* __restrict__ loss) {
    __shared__ __align__(16) unsigned short As[4][128 * 32];
    __shared__ __align__(16) unsigned short Bs[4][128 * 32];
    __shared__ float sqI[128], sqJ[128];
    __shared__ int   tIs[128], tJs[128];
    __shared__ float red[8];

    int tid = threadIdx.x;
    int wave = tid >> 6, lane = tid & 63;

    // decode (group g, slot s) -> (it, jt), jt >= it
    int g = blockIdx.x & 7, s = blockIdx.x >> 3;
    int sz0 = g + 1, sz1 = g + 9, sz2 = g + 17, sz3 = g + 25;
    int jt, it;
    if      (s < sz0)             { jt = g;      it = s; }
    else if (s < sz0 + sz1)       { jt = g + 8;  it = s - sz0; }
    else if (s < sz0 + sz1 + sz2) { jt = g + 16; it = s - sz0 - sz1; }
    else if (s < sz0 + sz1 + sz2 + sz3) { jt = g + 24; it = s - sz0 - sz1 - sz2; }
    else return;                                    // 112 idle filler blocks

    // staging: 16 global_load_lds(16B) per K-step, 2 per wave.
    // XOR-quad swizzle: logical quad q stored at physical quad p = q ^ ((row>>1)&3)
    const unsigned short* gp[2];
    unsigned short* lb[2];
    #pragma unroll
    for (int si = 0; si < 2; si++) {
        int gI = wave * 2 + si;             // 0..15 : <8 -> A tile, >=8 -> B tile
        int R  = gI * 16 + (lane >> 2);     // staging row 0..255
        int q  = (lane & 3) ^ ((R >> 1) & 3);
        int r  = R & 127;
        bool isA = R < 128;
        int grow = (isA ? it : jt) * 128 + r;
        const unsigned short* src = isA ? Xb : XWb;
        gp[si] = src + (size_t)grow * DIM + q * 8;
        lb[si] = (isA ? &As[0][0] : &Bs[0][0]) + (gI & 7) * (16 * 32);
    }

    // fragment LDS offsets (constant over k): A[m=lane&15][k=(lane>>4)*8+j]
    int lr = lane & 15, kq = lane >> 4;
    int offA[4], offB[2];
    int wrow = (wave >> 2) * 64, wcol = (wave & 3) * 32;
    #pragma unroll
    for (int mi = 0; mi < 4; mi++) {
        int row = wrow + mi * 16 + lr;
        offA[mi] = row * 32 + (kq ^ ((row >> 1) & 3)) * 8;
    }
    #pragma unroll
    for (int nj = 0; nj < 2; nj++) {
        int col = wcol + nj * 16 + lr;
        offB[nj] = col * 32 + (kq ^ ((col >> 1) & 3)) * 8;
    }

    f32x4 acc[4][2];
    #pragma unroll
    for (int i = 0; i < 4; i++)
        #pragma unroll
        for (int j = 0; j < 2; j++) acc[i][j] = (f32x4){0.f, 0.f, 0.f, 0.f};

    // prologue: stage K-steps 0,1,2 into buffers 0,1,2 (6 loads in flight/wave)
    #pragma unroll
    for (int st = 0; st < 3; st++)
        #pragma unroll
        for (int si = 0; si < 2; si++)
            async_cp16(gp[si] + st * 32, lb[si] + st * (128 * 32));

    for (int kk = 0; kk < 32; kk++) {
        // need step kk's staging done; leave steps kk+1,kk+2 (4 loads) in flight
        if      (kk < 30)  asm volatile("s_waitcnt vmcnt(4)" ::: "memory");
        else if (kk == 30) asm volatile("s_waitcnt vmcnt(2)" ::: "memory");
        else               asm volatile("s_waitcnt vmcnt(0)" ::: "memory");
        asm volatile("s_barrier" ::: "memory");
        if (kk < 29) {                      // prefetch kk+3 into (kk+3)&3
            int wr = (kk + 3) & 3;          // == (kk-1)&3: read finished pre-barrier
            #pragma unroll
            for (int si = 0; si < 2; si++)
                async_cp16(gp[si] + (kk + 3) * 32, lb[si] + wr * (128 * 32));
        }
        int rd = kk & 3;
        const unsigned short* Ab = As[rd];
        const unsigned short* Bb = Bs[rd];
        bf16x8 av[4], bv[2];
        #pragma unroll
        for (int i = 0; i < 4; i++) av[i] = *(const bf16x8*)(Ab + offA[i]);
        #pragma unroll
        for (int j = 0; j < 2; j++) bv[j] = *(const bf16x8*)(Bb + offB[j]);
        #pragma unroll
        for (int i = 0; i < 4; i++)
            #pragma unroll
            for (int j = 0; j < 2; j++)
                acc[i][j] = __builtin_amdgcn_mfma_f32_16x16x32_bf16(av[i], bv[j], acc[i][j], 0, 0, 0);
    }

    // epilogue: S = sq_i + sq_j - 2G, masked softplus, symmetric x2 off-diagonal
    __syncthreads();
    if (tid < 128)      { sqI[tid] = sq[it * 128 + tid]; tIs[tid] = tgt[it * 128 + tid]; }
    else if (tid < 256) { int u = tid - 128; sqJ[u] = sq[jt * 128 + u]; tJs[u] = tgt[jt * 128 + u]; }
    __syncthreads();

    float sum = 0.f;
    bool diagTile = (it == jt);
    #pragma unroll
    for (int j = 0; j < 2; j++) {
        int col = wcol + j * 16 + (lane & 15);            // C/D: col = lane&15
        float sj = sqJ[col]; int tj = tJs[col];
        #pragma unroll
        for (int i = 0; i < 4; i++) {
            int rbase = wrow + i * 16 + (lane >> 4) * 4;  // C/D: row = quad*4+reg
            #pragma unroll
            for (int r = 0; r < 4; r++) {
                int rowp = rbase + r;
                float S = sqI[rowp] + sj - 2.f * acc[i][j][r];
                float v;
                if (tIs[rowp] == tj) v = (diagTile && rowp == col) ? 0.f : softplus(-S);
                else                 v = softplus(S);
                sum += v;
            }
        }
    }
    float scale = (diagTile ? 1.f : 2.f) * (1.f / ((float)N_ROWS * (float)(N_ROWS - 1)));
    sum *= scale;
    for (int off = 32; off; off >>= 1) sum += __shfl_down(sum, off, 64);
    if (lane == 0) red[wave] = sum;
    __syncthreads();
    if (tid == 0) {
        float t = 0.f;
        #pragma unroll
        for (int wv = 0; wv < 8; wv++) t += red[wv];
        atomicAdd(loss, t);
    }
}

extern "C" void kernel_launch(void* const* d_in, const int* in_sizes, int n_in,
                              void* d_out, int out_size, void* d_ws, size_t ws_size,
                              hipStream_t stream) {
    const float* X  = (const float*)d_in[0];
    const int* tgt  = (const int*)d_in[1];
    float* out = (float*)d_out;
    char* ws = (char*)d_ws;
    const size_t MB = 1u << 20;

    float* w        = (float*)ws;                       // 4 KB
    float* sq       = (float*)(ws + 4096);              // 16 KB
    unsigned short* Xb  = (unsigned short*)(ws + 1 * MB);   // 8 MB
    unsigned short* XWb = (unsigned short*)(ws + 9 * MB);   // 8 MB
    float* csumR    = (float*)(ws + 17 * MB);           // 256 KB
    float* csqR     = (float*)(ws + 17 * MB + 256 * 1024); // 256 KB

    k_cstats  <<<256,  256, 0, stream>>>(X, tgt, csumR, csqR);
    k_weights <<<4,    256, 0, stream>>>(tgt, csumR, csqR, w, out);
    k_prep    <<<4096, 256, 0, stream>>>(X, w, Xb, XWb, sq);
    k_gemm_loss<<<640, 512, 0, stream>>>(Xb, XWb, sq, tgt, out);
}

// Round 6
// 125.237 us; speedup vs baseline: 1.2095x; 1.0214x over previous
//
#include <hip/hip_runtime.h>
#include <stdint.h>

#define N_ROWS 4096
#define DIM    1024
#define NCLS   64
#define EPSV   0.1f

typedef __attribute__((ext_vector_type(4))) float f32x4;

__device__ __forceinline__ void async_cp16(const void* g, void* l) {
    __builtin_amdgcn_global_load_lds((const __attribute__((address_space(1))) void*)g,
                                     (__attribute__((address_space(3))) void*)l,
                                     16, 0, 0);
}

__device__ __forceinline__ float softplus(float x) {
    return fmaxf(x, 0.f) + __logf(1.f + __expf(-fabsf(x)));
}

// ---------------- K1: per-class sum/sqsum via row gather ---------------------
__global__ __launch_bounds__(256) void k_cstats(const float* __restrict__ X,
                                                const int* __restrict__ tgt,
                                                float* __restrict__ csumR,
                                                float* __restrict__ csqR) {
    __shared__ int rows[N_ROWS];
    __shared__ int nrows_s;
    int tid = threadIdx.x;
    int c = blockIdx.x >> 2, q = blockIdx.x & 3;
    if (tid == 0) nrows_s = 0;
    __syncthreads();
    for (int i = tid; i < N_ROWS; i += 256)
        if (tgt[i] == c) { int p = atomicAdd(&nrows_s, 1); rows[p] = i; }
    __syncthreads();
    int n = nrows_s;
    int d = q * 256 + tid;
    float s = 0.f, qq = 0.f;
    #pragma unroll 4
    for (int r = 0; r < n; r++) {
        float x = X[(size_t)rows[r] * DIM + d];
        s += x; qq += x * x;
    }
    csumR[c * DIM + d] = s;
    csqR [c * DIM + d] = qq;
}

// ---------------- K2: counts + weights + fp8 scale + zero loss ---------------
__global__ __launch_bounds__(1024) void k_weights(const int* __restrict__ tgt,
                                                  const float* __restrict__ csumR,
                                                  const float* __restrict__ csqR,
                                                  float* __restrict__ w,
                                                  float* __restrict__ scal,
                                                  float* __restrict__ loss_out) {
    __shared__ int hist[NCLS];
    __shared__ float redw[16];
    int tid = threadIdx.x;
    if (tid < NCLS) hist[tid] = 0;
    __syncthreads();
    for (int i = tid; i < N_ROWS; i += 1024) atomicAdd(&hist[tgt[i]], 1);
    __syncthreads();
    long long sp = 0, ss = 0;
    for (int c = 0; c < NCLS; c++) { long long cc = hist[c]; sp += cc * (cc - 1); ss += cc * cc; }
    float cnt_pos = (float)sp;
    float cnt_neg = (float)((long long)N_ROWS * N_ROWS - ss);
    int d = tid;                                // 0..1023
    float A = 0.f, X2 = 0.f, T = 0.f, SS = 0.f;
    #pragma unroll 8
    for (int c = 0; c < NCLS; c++) {
        float s = csumR[c * DIM + d];
        float q = csqR [c * DIM + d];
        A += (float)hist[c] * q; X2 += q; T += s; SS += s * s;
    }
    float posnum = 2.f * (A - SS);
    float negnum = 2.f * ((float)N_ROWS * X2 - A - T * T + SS);
    float wd = cnt_neg / (negnum + EPSV) - cnt_pos / (posnum + EPSV);
    w[d] = wd;
    // reduce mean(w^2) -> power-of-two scale for fp8 XW
    float m = wd * wd;
    for (int off = 32; off; off >>= 1) m += __shfl_down(m, off, 64);
    int wv = tid >> 6, ln = tid & 63;
    if (ln == 0) redw[wv] = m;
    __syncthreads();
    if (tid == 0) {
        float ms = 0.f;
        #pragma unroll
        for (int i = 0; i < 16; i++) ms += redw[i];
        ms /= 1024.f;
        float sw = exp2f(roundf(log2f(sqrtf(ms) + 1e-30f)));
        scal[0] = sw;
        loss_out[0] = 0.0f;
    }
}

// ---------------- K3: xw, sq (fp32 exact), fp8 casts -------------------------
__global__ __launch_bounds__(256) void k_prep(const float* __restrict__ X,
                                              const float* __restrict__ w,
                                              const float* __restrict__ scal,
                                              unsigned int* __restrict__ Xb8,
                                              unsigned int* __restrict__ XWb8,
                                              float* __restrict__ sq) {
    int row = blockIdx.x, tid = threadIdx.x;
    float inv_sw = 1.0f / scal[0];
    float4 x  = ((const float4*)(X + (size_t)row * DIM))[tid];
    float4 ww = ((const float4*)w)[tid];
    float4 xw = make_float4(x.x * ww.x, x.y * ww.y, x.z * ww.z, x.w * ww.w);
    float p = x.x * xw.x + x.y * xw.y + x.z * xw.z + x.w * xw.w;
    unsigned ux = __builtin_amdgcn_cvt_pk_fp8_f32(x.x, x.y, 0, false);
    ux = __builtin_amdgcn_cvt_pk_fp8_f32(x.z, x.w, ux, true);
    unsigned uw = __builtin_amdgcn_cvt_pk_fp8_f32(xw.x * inv_sw, xw.y * inv_sw, 0, false);
    uw = __builtin_amdgcn_cvt_pk_fp8_f32(xw.z * inv_sw, xw.w * inv_sw, uw, true);
    Xb8 [row * 256 + tid] = ux;
    XWb8[row * 256 + tid] = uw;
    for (int off = 32; off; off >>= 1) p += __shfl_down(p, off, 64);
    __shared__ float red[4];
    int wv = tid >> 6, ln = tid & 63;
    if (ln == 0) red[wv] = p;
    __syncthreads();
    if (tid == 0) sq[row] = red[0] + red[1] + red[2] + red[3];
}

// ---------------- K4: fused fp8 MFMA gram + softplus + masked mean -----------
// 128x128 tiles, balanced XCD groups: group g owns jt in {g,15-g,16+g,31-g}
// = exactly 66 tiles; 528 blocks. 512 thr = 8 waves (2x4), wave = 64x32
// (4x2 frags of 16x16x32 fp8). Depth-3 pipeline: 4 LDS buffer pairs (4KB
// each), 1 staging instr/wave/step, raw s_barrier + manual vmcnt.
__global__ __launch_bounds__(512) void k_gemm_loss(const unsigned char* __restrict__ Xb8,
                                                   const unsigned char* __restrict__ XWb8,
                                                   const float* __restrict__ sq,
                                                   const int* __restrict__ tgt,
                                                   const float* __restrict__ scal,
                                                   float* __restrict__ loss) {
    __shared__ __align__(16) unsigned char As[4][128 * 32];
    __shared__ __align__(16) unsigned char Bs[4][128 * 32];
    __shared__ float sqI[128], sqJ[128];
    __shared__ int   tIs[128], tJs[128];
    __shared__ float red[8];

    int tid = threadIdx.x;
    int wave = tid >> 6, lane = tid & 63;

    // balanced triangular decode
    int g = blockIdx.x & 7, s = blockIdx.x >> 3;
    int j0 = g, j1 = 15 - g, j2 = 16 + g, j3 = 31 - g;
    int n0 = j0 + 1, n1 = j1 + 1, n2 = j2 + 1;
    int jt, it;
    if      (s < n0)           { jt = j0; it = s; }
    else if (s < n0 + n1)      { jt = j1; it = s - n0; }
    else if (s < n0 + n1 + n2) { jt = j2; it = s - n0 - n1; }
    else                       { jt = j3; it = s - n0 - n1 - n2; }

    // staging: 8 instrs/block-step, 1 per wave. Wave covers 32 rows of one
    // slab; lane -> row r=(lane>>1), 16B half h=lane&1. Half-XOR swizzle
    // SW(r)=((r>>1)^(r>>2))&1 gives 2-way-only (free) ds_read_b64 conflicts.
    bool isA = wave < 4;
    int gIa = wave & 3;
    int r_loc = gIa * 32 + (lane >> 1);
    int swb = ((r_loc >> 1) ^ (r_loc >> 2)) & 1;
    int h_src = (lane & 1) ^ swb;
    int grow = (isA ? it : jt) * 128 + r_loc;
    const unsigned char* gp = (isA ? Xb8 : XWb8) + (size_t)grow * DIM + h_src * 16;
    unsigned char* lbase = (isA ? &As[0][0] : &Bs[0][0]) + gIa * 1024;

    // fragment LDS offsets: A[m=lane&15][k=(lane>>4)*8+j], 8B per lane
    int lr = lane & 15, kq = lane >> 4;
    int offA[4], offB[2];
    int wrow = (wave >> 2) * 64, wcol = (wave & 3) * 32;
    #pragma unroll
    for (int mi = 0; mi < 4; mi++) {
        int row = wrow + mi * 16 + lr;
        offA[mi] = row * 32 + ((kq ^ ((((row >> 1) ^ (row >> 2)) & 1) << 1)) * 8);
    }
    #pragma unroll
    for (int nj = 0; nj < 2; nj++) {
        int col = wcol + nj * 16 + lr;
        offB[nj] = col * 32 + ((kq ^ ((((col >> 1) ^ (col >> 2)) & 1) << 1)) * 8);
    }

    f32x4 acc[4][2];
    #pragma unroll
    for (int i = 0; i < 4; i++)
        #pragma unroll
        for (int j = 0; j < 2; j++) acc[i][j] = (f32x4){0.f, 0.f, 0.f, 0.f};

    // prologue: stage K-steps 0,1,2 into buffers 0,1,2 (3 loads in flight/wave)
    #pragma unroll
    for (int st = 0; st < 3; st++) async_cp16(gp + st * 32, lbase + st * (128 * 32));

    for (int kk = 0; kk < 32; kk++) {
        if      (kk < 30)  asm volatile("s_waitcnt vmcnt(2)" ::: "memory");
        else if (kk == 30) asm volatile("s_waitcnt vmcnt(1)" ::: "memory");
        else               asm volatile("s_waitcnt vmcnt(0)" ::: "memory");
        asm volatile("s_barrier" ::: "memory");
        if (kk < 29) {                      // prefetch kk+3 into (kk+3)&3
            async_cp16(gp + (kk + 3) * 32, lbase + ((kk + 3) & 3) * (128 * 32));
        }
        int rd = kk & 3;
        const unsigned char* Ab = As[rd];
        const unsigned char* Bb = Bs[rd];
        long long av[4], bv[2];
        #pragma unroll
        for (int i = 0; i < 4; i++) av[i] = *(const long long*)(Ab + offA[i]);
        #pragma unroll
        for (int j = 0; j < 2; j++) bv[j] = *(const long long*)(Bb + offB[j]);
        #pragma unroll
        for (int i = 0; i < 4; i++)
            #pragma unroll
            for (int j = 0; j < 2; j++)
                acc[i][j] = __builtin_amdgcn_mfma_f32_16x16x32_fp8_fp8(av[i], bv[j], acc[i][j], 0, 0, 0);
    }

    // epilogue: S = sq_i + sq_j - 2*sw*G', masked softplus, x2 off-diagonal
    __syncthreads();
    if (tid < 128)      { sqI[tid] = sq[it * 128 + tid]; tIs[tid] = tgt[it * 128 + tid]; }
    else if (tid < 256) { int u = tid - 128; sqJ[u] = sq[jt * 128 + u]; tJs[u] = tgt[jt * 128 + u]; }
    __syncthreads();

    float sw2 = 2.0f * scal[0];
    float sum = 0.f;
    bool diagTile = (it == jt);
    #pragma unroll
    for (int j = 0; j < 2; j++) {
        int col = wcol + j * 16 + (lane & 15);            // C/D: col = lane&15
        float sj = sqJ[col]; int tj = tJs[col];
        #pragma unroll
        for (int i = 0; i < 4; i++) {
            int rbase = wrow + i * 16 + (lane >> 4) * 4;  // C/D: row = quad*4+reg
            #pragma unroll
            for (int r = 0; r < 4; r++) {
                int rowp = rbase + r;
                float S = sqI[rowp] + sj - sw2 * acc[i][j][r];
                float v;
                if (tIs[rowp] == tj) v = (diagTile && rowp == col) ? 0.f : softplus(-S);
                else                 v = softplus(S);
                sum += v;
            }
        }
    }
    float scale = (diagTile ? 1.f : 2.f) * (1.f / ((float)N_ROWS * (float)(N_ROWS - 1)));
    sum *= scale;
    for (int off = 32; off; off >>= 1) sum += __shfl_down(sum, off, 64);
    if (lane == 0) red[wave] = sum;
    __syncthreads();
    if (tid == 0) {
        float t = 0.f;
        #pragma unroll
        for (int wv = 0; wv < 8; wv++) t += red[wv];
        atomicAdd(loss, t);
    }
}

extern "C" void kernel_launch(void* const* d_in, const int* in_sizes, int n_in,
                              void* d_out, int out_size, void* d_ws, size_t ws_size,
                              hipStream_t stream) {
    const float* X  = (const float*)d_in[0];
    const int* tgt  = (const int*)d_in[1];
    float* out = (float*)d_out;
    char* ws = (char*)d_ws;
    const size_t MB = 1u << 20;

    float* w      = (float*)ws;                         // 4 KB
    float* sq     = (float*)(ws + 4096);                // 16 KB
    float* scal   = (float*)(ws + 24576);               // 4 B
    unsigned int* Xb8  = (unsigned int*)(ws + 1 * MB);  // 4 MB
    unsigned int* XWb8 = (unsigned int*)(ws + 5 * MB);  // 4 MB
    float* csumR  = (float*)(ws + 9 * MB);              // 256 KB
    float* csqR   = (float*)(ws + 9 * MB + 256 * 1024); // 256 KB

    k_cstats  <<<256,  256, 0, stream>>>(X, tgt, csumR, csqR);
    k_weights <<<1,   1024, 0, stream>>>(tgt, csumR, csqR, w, scal, out);
    k_prep    <<<4096, 256, 0, stream>>>(X, w, scal, Xb8, XWb8, sq);
    k_gemm_loss<<<528, 512, 0, stream>>>((const unsigned char*)Xb8, (const unsigned char*)XWb8,
                                         sq, tgt, scal, out);
}